// Round 8
// baseline (47.262 us; speedup 1.0000x reference)
//
#include <hip/hip_runtime.h>

#define NB 64
#define NT 48
#define NF 128
#define NE 64
#define NCD 32

#define LOG2E 1.4426950408889634f
#define SCLO -7.213475204444817f   // -5 * log2e
#define SCHI  7.213475204444817f

typedef __attribute__((ext_vector_type(8))) short bf16x8;
typedef __attribute__((ext_vector_type(4))) float f32x4;
typedef __attribute__((ext_vector_type(2))) uint u32x2;

// ---- ws layout (bytes) ----
#define WS_MFLAG 0        // 8192 u32
#define WS_DB    32768    // 8192 u16: bf16(e0-e1)
#define WS_E1B   49152    // bf16(e1)
#define WS_EMB   65536    // bf16(emiss)
#define WS_WLB   81920    // bf16(attn_w * log2e)
#define WS_WT    98304    // [32][128] u16 compress_w^T
#define WS_BL    106496   // 128 f32 bias*log2e

__device__ __forceinline__ ushort f2bf(float x) {
    union { float f; uint u; } v; v.f = x;
    uint r = v.u + 0x7fffu + ((v.u >> 16) & 1u);   // RNE
    return (ushort)(r >> 16);
}
__device__ __forceinline__ uint pk_bf16(float lo, float hi) {   // v_cvt_pk_bf16_f32
    uint r; asm("v_cvt_pk_bf16_f32 %0, %1, %2" : "=v"(r) : "v"(lo), "v"(hi)); return r;
}
__device__ __forceinline__ float bflo(uint u) { union { uint u; float f; } v; v.u = u << 16; return v.f; }
__device__ __forceinline__ float bfhi(uint u) { union { uint u; float f; } v; v.u = u & 0xffff0000u; return v.f; }

// hardware transpose read: lane reads 4 bf16 at u16-stride 16 from its own addr
#define TRR(dst, addr, IMM) \
    asm volatile("ds_read_b64_tr_b16 %0, %1 offset:" IMM : "=v"(dst) : "v"(addr))

// softmax step for one 4-col tile (base-2 exp, diag zero, pack to bf16 pair)
#define SM_STEP(ST, PP, JT, RSA) do {                                     \
    f32x4 v_ = ST[JT];                                                    \
    float e0_ = exp2f(__builtin_amdgcn_fmed3f(v_[0], SCLO, SCHI));        \
    float e1_ = exp2f(__builtin_amdgcn_fmed3f(v_[1], SCLO, SCHI));        \
    float e2_ = exp2f(__builtin_amdgcn_fmed3f(v_[2], SCLO, SCHI));        \
    float e3_ = exp2f(__builtin_amdgcn_fmed3f(v_[3], SCLO, SCHI));        \
    if ((JT) == wv) {                                                     \
        const bool on_ = (lg == (lr >> 2));                               \
        e0_ = (on_ && (lr & 3) == 0) ? 0.f : e0_;                         \
        e1_ = (on_ && (lr & 3) == 1) ? 0.f : e1_;                         \
        e2_ = (on_ && (lr & 3) == 2) ? 0.f : e2_;                         \
        e3_ = (on_ && (lr & 3) == 3) ? 0.f : e3_;                         \
    }                                                                     \
    RSA[0] += e0_; RSA[1] += e1_; RSA[2] += e2_; RSA[3] += e3_;           \
    PP[2 * (JT)]     = pk_bf16(e0_, e1_);                                 \
    PP[2 * (JT) + 1] = pk_bf16(e2_, e3_);                                 \
} while (0)

// ---------------- kernel 1: prep ----------------
__global__ __launch_bounds__(256) void prep_kernel(
    const int* __restrict__ mask, const float* __restrict__ e0, const float* __restrict__ e1,
    const float* __restrict__ em, const float* __restrict__ aw, const float* __restrict__ ab,
    const float* __restrict__ cw,
    uint* __restrict__ mflag, ushort* __restrict__ db, ushort* __restrict__ e1b,
    ushort* __restrict__ emb, ushort* __restrict__ wlb, ushort* __restrict__ wt,
    float* __restrict__ bl)
{
    const int blk = blockIdx.x, tid = threadIdx.x;
    if (blk < 32) {                     // tables -> bf16 (+ D = e0-e1, w*log2e)
        int idx = blk * 256 + tid;      // 8192
        float e1v = e1[idx];
        e1b[idx] = f2bf(e1v);
        emb[idx] = f2bf(em[idx]);
        db[idx]  = f2bf(e0[idx] - e1v);
        wlb[idx] = f2bf(aw[idx] * LOG2E);
    } else if (blk < 64) {              // m[b,f] = any_t mask
        int idx = (blk - 32) * 256 + tid;
        int b = idx >> 7, f = idx & 127;
        const int* p = mask + b * (NT * NF) + f;
        int s = 0;
#pragma unroll
        for (int t = 0; t < NT; ++t) s += p[t * NF];
        mflag[idx] = (s != 0) ? 1u : 0u;
    } else if (blk < 80) {              // compress_w [128][32] -> wt bf16 [32][128]
        int idx = (blk - 64) * 256 + tid;
        int k = idx >> 5, d = idx & 31;
        wt[d * 128 + k] = f2bf(cw[idx]);
    } else {                            // bias * log2e
        if (tid < NF) bl[tid] = ab[tid] * LOG2E;
    }
}

// ---------------- kernel 2: dual-(b,t) pipeline, fine-grained cross-chain interleave ----
// LDS: sC[2][9248] u16 + sPA[2][8*1152] u16 = 73856 B -> 2 blocks/CU.
// Schedule: S(0) | S(1)+SM(0) | AGG(0)+SM(1) | AGG(1)+EPI(0) | EPI(1) | OUT(0)+OUT(1)
__global__ __launch_bounds__(512, 4) void fused_kernel(
    const float* __restrict__ input_x, const uint* __restrict__ mflag,
    const ushort* __restrict__ db, const ushort* __restrict__ e1b, const ushort* __restrict__ emb,
    const ushort* __restrict__ wlb, const float* __restrict__ blog,
    const ushort* __restrict__ wt, float* __restrict__ out)
{
    __shared__ ushort sC[2 * 9248];
    __shared__ ushort sPA[2 * 8 * 1152];

    const int tid = threadIdx.x;
    const int blk = blockIdx.x;
    const int b   = blk / 24;
    const int bt0 = b * NT + (blk % 24) * 2;
    const int bt1 = bt0 + 1;

    const int wv = tid >> 6, ln = tid & 63;
    const int lr = ln & 15, lg = ln >> 4;
    const int i0 = wv << 4, irow = i0 + lr;

    // ---- hoisted per-lane globals (shared across both chains) ----
    const float bl = blog[irow];
    const float x0 = input_x[bt0 * NF + irow];
    const float x1 = input_x[bt1 * NF + irow];
    const ushort* Mrow = (mflag[b * NF + irow] ? e1b : emb) + irow * NE;
    const ushort* Drow = db + irow * NE;
    const ushort* Wrow = wlb + irow * NE;

    const int sbase = (lg >> 1) * 2312 + (lr >> 2) * 72 + (lr & 3) * 16 + (lg & 1) * 8;

    ushort* sC0 = sC;
    ushort* sC1 = sC + 9248;
    ushort* strip0 = &sPA[wv * 1152];
    ushort* strip1 = &sPA[9216 + wv * 1152];

    // ---- phase 1: unpack D/M/W once; c(t0), c(t1) to LDS; CW-frags in regs ----
    bf16x8 cwf0[2], cwf1[2];
#pragma unroll
    for (int ks = 0; ks < 2; ++ks) {
        const int eo = ks * 32 + lg * 8;
        uint d4[4], m4[4], w4[4];
        *(uint4*)d4 = *(const uint4*)(Drow + eo);
        *(uint4*)m4 = *(const uint4*)(Mrow + eo);
        *(uint4*)w4 = *(const uint4*)(Wrow + eo);
        uint cb0[4], cb1[4];
        union { uint u[4]; bf16x8 v; } cw0, cw1;
#pragma unroll
        for (int j = 0; j < 4; ++j) {
            float dlo = bflo(d4[j]), dhi = bfhi(d4[j]);
            float mlo = bflo(m4[j]), mhi = bfhi(m4[j]);
            float wlo = bflo(w4[j]), whi = bfhi(w4[j]);
            float c0lo = fmaf(x0, dlo, mlo), c0hi = fmaf(x0, dhi, mhi);
            float c1lo = fmaf(x1, dlo, mlo), c1hi = fmaf(x1, dhi, mhi);
            cb0[j] = pk_bf16(c0lo, c0hi);
            cb1[j] = pk_bf16(c1lo, c1hi);
            cw0.u[j] = pk_bf16(c0lo * wlo, c0hi * whi);
            cw1.u[j] = pk_bf16(c1lo * wlo, c1hi * whi);
        }
        cwf0[ks] = cw0.v; cwf1[ks] = cw1.v;
        *(uint4*)&sC0[sbase + wv * 288 + ks * 4624] = *(uint4*)cb0;
        *(uint4*)&sC1[sbase + wv * 288 + ks * 4624] = *(uint4*)cb1;
    }
    __syncthreads();                    // the ONLY barrier

    f32x4 st0[8], st1[8];
    uint pp0[16], pp1[16];
    float rsa0[4] = {0.f, 0.f, 0.f, 0.f}, rsa1[4] = {0.f, 0.f, 0.f, 0.f};

    // ---- stage A: S(c0) ----
#pragma unroll
    for (int jt = 0; jt < 8; ++jt) {
        f32x4 a = (f32x4){bl, bl, bl, bl};
        bf16x8 a0 = *(bf16x8*)&sC0[sbase + jt * 288];
        a = __builtin_amdgcn_mfma_f32_16x16x32_bf16(a0, cwf0[0], a, 0, 0, 0);
        bf16x8 a1 = *(bf16x8*)&sC0[sbase + jt * 288 + 4624];
        a = __builtin_amdgcn_mfma_f32_16x16x32_bf16(a1, cwf0[1], a, 0, 0, 0);
        st0[jt] = a;
    }

    // ---- stage B: S(c1) MFMA interleaved with SM(c0) VALU ----
#pragma unroll
    for (int jt = 0; jt < 8; ++jt) {
        f32x4 a = (f32x4){bl, bl, bl, bl};
        bf16x8 a0 = *(bf16x8*)&sC1[sbase + jt * 288];
        a = __builtin_amdgcn_mfma_f32_16x16x32_bf16(a0, cwf1[0], a, 0, 0, 0);
        bf16x8 a1 = *(bf16x8*)&sC1[sbase + jt * 288 + 4624];
        a = __builtin_amdgcn_mfma_f32_16x16x32_bf16(a1, cwf1[1], a, 0, 0, 0);
        st1[jt] = a;
        SM_STEP(st0, pp0, jt, rsa0);
    }
    float rs0 = (rsa0[0] + rsa0[1]) + (rsa0[2] + rsa0[3]);
    rs0 += __shfl_xor(rs0, 16);
    rs0 += __shfl_xor(rs0, 32);
    const float inv0 = 1.0f / (rs0 + 1e-8f);

    // ---- stage C: AGG(c0) interleaved with SM(c1) ----
    const uint b0addr = (uint)(uintptr_t)sC0;
    const uint b1addr = (uint)(uintptr_t)sC1;
    f32x4 ag0[4], ag1[4];
#pragma unroll
    for (int et = 0; et < 4; ++et) { ag0[et] = (f32x4){0.f, 0.f, 0.f, 0.f}; ag1[et] = (f32x4){0.f, 0.f, 0.f, 0.f}; }
#pragma unroll
    for (int ks = 0; ks < 4; ++ks) {
        *(u32x2*)&strip0[lr * 72 + lg * 4]      = (u32x2){pp0[4 * ks],     pp0[4 * ks + 1]};
        *(u32x2*)&strip0[lr * 72 + 16 + lg * 4] = (u32x2){pp0[4 * ks + 2], pp0[4 * ks + 3]};
        bf16x8 pf = *(bf16x8*)&strip0[lr * 72 + lg * 8];
        const uint tb = b0addr + 2u * (uint)(144 * lg + lr) + 1152u * (uint)ks;
        u32x2 c0a, c0b, c1a, c1b, c2a, c2b, c3a, c3b;
        TRR(c0a, tb, "0");     TRR(c0b, tb, "144");
        TRR(c1a, tb, "4624");  TRR(c1b, tb, "4768");
        TRR(c2a, tb, "9248");  TRR(c2b, tb, "9392");
        TRR(c3a, tb, "13872"); TRR(c3b, tb, "14016");
        // VALU filler while tr-reads are in flight:
        SM_STEP(st1, pp1, 2 * ks, rsa1);
        SM_STEP(st1, pp1, 2 * ks + 1, rsa1);
        asm volatile("s_waitcnt lgkmcnt(0)" ::: "memory");
        __builtin_amdgcn_sched_barrier(0);
        union { u32x2 d[2]; bf16x8 v; } a0, a1, a2, a3;
        a0.d[0] = c0a; a0.d[1] = c0b;
        a1.d[0] = c1a; a1.d[1] = c1b;
        a2.d[0] = c2a; a2.d[1] = c2b;
        a3.d[0] = c3a; a3.d[1] = c3b;
        ag0[0] = __builtin_amdgcn_mfma_f32_16x16x32_bf16(a0.v, pf, ag0[0], 0, 0, 0);
        ag0[1] = __builtin_amdgcn_mfma_f32_16x16x32_bf16(a1.v, pf, ag0[1], 0, 0, 0);
        ag0[2] = __builtin_amdgcn_mfma_f32_16x16x32_bf16(a2.v, pf, ag0[2], 0, 0, 0);
        ag0[3] = __builtin_amdgcn_mfma_f32_16x16x32_bf16(a3.v, pf, ag0[3], 0, 0, 0);
    }
    float rs1 = (rsa1[0] + rsa1[1]) + (rsa1[2] + rsa1[3]);
    rs1 += __shfl_xor(rs1, 16);
    rs1 += __shfl_xor(rs1, 32);
    const float inv1 = 1.0f / (rs1 + 1e-8f);

    // ---- Wt B-frag prefetch (consumed in OUT; latency hides under stage D) ----
    bf16x8 wf[8];
#pragma unroll
    for (int ks = 0; ks < 4; ++ks)
#pragma unroll
        for (int dt = 0; dt < 2; ++dt)
            wf[ks * 2 + dt] = *(const bf16x8*)(wt + (dt * 16 + lr) * 128 + ks * 32 + lg * 8);

    // ---- stage D: AGG(c1) interleaved with EPI(c0) ----
    const int ebase = (wv * 4 + (lr >> 2)) * 72 + (lr & 3) * 16 + lg * 4;
#pragma unroll
    for (int ks = 0; ks < 4; ++ks) {
        *(u32x2*)&strip1[lr * 72 + lg * 4]      = (u32x2){pp1[4 * ks],     pp1[4 * ks + 1]};
        *(u32x2*)&strip1[lr * 72 + 16 + lg * 4] = (u32x2){pp1[4 * ks + 2], pp1[4 * ks + 3]};
        bf16x8 pf = *(bf16x8*)&strip1[lr * 72 + lg * 8];
        const uint tb = b1addr + 2u * (uint)(144 * lg + lr) + 1152u * (uint)ks;
        u32x2 c0a, c0b, c1a, c1b, c2a, c2b, c3a, c3b;
        TRR(c0a, tb, "0");     TRR(c0b, tb, "144");
        TRR(c1a, tb, "4624");  TRR(c1b, tb, "4768");
        TRR(c2a, tb, "9248");  TRR(c2b, tb, "9392");
        TRR(c3a, tb, "13872"); TRR(c3b, tb, "14016");
        // VALU filler: EPI(c0) chunk et=ks (normalize, .*C, relu, A2 -> strip0)
        {
            u32x2 cb2 = *(u32x2*)&sC0[ebase + ks * 2312];
            float a0f = fmaxf(ag0[ks][0] * inv0 * bflo(cb2.x), 0.f);
            float a1f = fmaxf(ag0[ks][1] * inv0 * bfhi(cb2.x), 0.f);
            float a2f = fmaxf(ag0[ks][2] * inv0 * bflo(cb2.y), 0.f);
            float a3f = fmaxf(ag0[ks][3] * inv0 * bfhi(cb2.y), 0.f);
            *(u32x2*)&strip0[lr * 72 + ks * 16 + lg * 4] = (u32x2){pk_bf16(a0f, a1f), pk_bf16(a2f, a3f)};
        }
        asm volatile("s_waitcnt lgkmcnt(0)" ::: "memory");
        __builtin_amdgcn_sched_barrier(0);
        union { u32x2 d[2]; bf16x8 v; } a0, a1, a2, a3;
        a0.d[0] = c0a; a0.d[1] = c0b;
        a1.d[0] = c1a; a1.d[1] = c1b;
        a2.d[0] = c2a; a2.d[1] = c2b;
        a3.d[0] = c3a; a3.d[1] = c3b;
        ag1[0] = __builtin_amdgcn_mfma_f32_16x16x32_bf16(a0.v, pf, ag1[0], 0, 0, 0);
        ag1[1] = __builtin_amdgcn_mfma_f32_16x16x32_bf16(a1.v, pf, ag1[1], 0, 0, 0);
        ag1[2] = __builtin_amdgcn_mfma_f32_16x16x32_bf16(a2.v, pf, ag1[2], 0, 0, 0);
        ag1[3] = __builtin_amdgcn_mfma_f32_16x16x32_bf16(a3.v, pf, ag1[3], 0, 0, 0);
    }

    // ---- stage E: EPI(c1) ----
#pragma unroll
    for (int et = 0; et < 4; ++et) {
        u32x2 cb2 = *(u32x2*)&sC1[ebase + et * 2312];
        float a0f = fmaxf(ag1[et][0] * inv1 * bflo(cb2.x), 0.f);
        float a1f = fmaxf(ag1[et][1] * inv1 * bfhi(cb2.x), 0.f);
        float a2f = fmaxf(ag1[et][2] * inv1 * bflo(cb2.y), 0.f);
        float a3f = fmaxf(ag1[et][3] * inv1 * bfhi(cb2.y), 0.f);
        *(u32x2*)&strip1[lr * 72 + et * 16 + lg * 4] = (u32x2){pk_bf16(a0f, a1f), pk_bf16(a2f, a3f)};
    }

    // ---- stage F: OUT(c0) and OUT(c1) interleaved ----
    f32x4 oc0[2], oc1[2];
    oc0[0] = (f32x4){0.f, 0.f, 0.f, 0.f}; oc0[1] = (f32x4){0.f, 0.f, 0.f, 0.f};
    oc1[0] = (f32x4){0.f, 0.f, 0.f, 0.f}; oc1[1] = (f32x4){0.f, 0.f, 0.f, 0.f};
#pragma unroll
    for (int ks = 0; ks < 4; ++ks) {
        bf16x8 afr0, afr1;
        if (ks < 2) {
            const uint4 cc0 = *(uint4*)&sC0[sbase + wv * 288 + ks * 4624];
            const uint4 cc1 = *(uint4*)&sC1[sbase + wv * 288 + ks * 4624];
            union { uint u[4]; bf16x8 v; } r0, r1;
            asm("v_pk_max_i16 %0, %1, 0" : "=v"(r0.u[0]) : "v"(cc0.x));
            asm("v_pk_max_i16 %0, %1, 0" : "=v"(r0.u[1]) : "v"(cc0.y));
            asm("v_pk_max_i16 %0, %1, 0" : "=v"(r0.u[2]) : "v"(cc0.z));
            asm("v_pk_max_i16 %0, %1, 0" : "=v"(r0.u[3]) : "v"(cc0.w));
            asm("v_pk_max_i16 %0, %1, 0" : "=v"(r1.u[0]) : "v"(cc1.x));
            asm("v_pk_max_i16 %0, %1, 0" : "=v"(r1.u[1]) : "v"(cc1.y));
            asm("v_pk_max_i16 %0, %1, 0" : "=v"(r1.u[2]) : "v"(cc1.z));
            asm("v_pk_max_i16 %0, %1, 0" : "=v"(r1.u[3]) : "v"(cc1.w));
            afr0 = r0.v; afr1 = r1.v;
        } else {
            afr0 = *(bf16x8*)&strip0[lr * 72 + (ks - 2) * 32 + lg * 8];
            afr1 = *(bf16x8*)&strip1[lr * 72 + (ks - 2) * 32 + lg * 8];
        }
        oc0[0] = __builtin_amdgcn_mfma_f32_16x16x32_bf16(afr0, wf[ks * 2 + 0], oc0[0], 0, 0, 0);
        oc0[1] = __builtin_amdgcn_mfma_f32_16x16x32_bf16(afr0, wf[ks * 2 + 1], oc0[1], 0, 0, 0);
        oc1[0] = __builtin_amdgcn_mfma_f32_16x16x32_bf16(afr1, wf[ks * 2 + 0], oc1[0], 0, 0, 0);
        oc1[1] = __builtin_amdgcn_mfma_f32_16x16x32_bf16(afr1, wf[ks * 2 + 1], oc1[1], 0, 0, 0);
    }
    float* op0 = out + bt0 * (NF * NCD);
    float* op1 = out + bt1 * (NF * NCD);
#pragma unroll
    for (int dt = 0; dt < 2; ++dt)
#pragma unroll
        for (int r = 0; r < 4; ++r) {
            op0[(i0 + lg * 4 + r) * NCD + dt * 16 + lr] = oc0[dt][r];
            op1[(i0 + lg * 4 + r) * NCD + dt * 16 + lr] = oc1[dt][r];
        }
}

extern "C" void kernel_launch(void* const* d_in, const int* in_sizes, int n_in,
                              void* d_out, int out_size, void* d_ws, size_t ws_size,
                              hipStream_t stream) {
    const float* input_x       = (const float*)d_in[0];
    const int*   mask          = (const int*)d_in[1];
    const float* embed0        = (const float*)d_in[2];
    const float* embed1        = (const float*)d_in[3];
    const float* embed_missing = (const float*)d_in[4];
    const float* attn_w        = (const float*)d_in[5];
    const float* attn_b        = (const float*)d_in[6];
    const float* compress_w    = (const float*)d_in[7];
    float* out = (float*)d_out;

    char* ws = (char*)d_ws;
    uint*   mflag = (uint*)(ws + WS_MFLAG);
    ushort* dbp   = (ushort*)(ws + WS_DB);
    ushort* e1bp  = (ushort*)(ws + WS_E1B);
    ushort* embp  = (ushort*)(ws + WS_EMB);
    ushort* wlbp  = (ushort*)(ws + WS_WLB);
    ushort* wtp   = (ushort*)(ws + WS_WT);
    float*  blp   = (float*)(ws + WS_BL);

    hipLaunchKernelGGL(prep_kernel, dim3(81), dim3(256), 0, stream,
                       mask, embed0, embed1, embed_missing, attn_w, attn_b, compress_w,
                       mflag, dbp, e1bp, embp, wlbp, wtp, blp);
    hipLaunchKernelGGL(fused_kernel, dim3(NB * NT / 2), dim3(512), 0, stream,
                       input_x, mflag, dbp, e1bp, embp, wlbp, blp, wtp, out);
}

// Round 9
// 43.113 us; speedup vs baseline: 1.0962x; 1.0962x over previous
//
#include <hip/hip_runtime.h>

#define NB 64
#define NT 48
#define NF 128
#define NE 64
#define NCD 32

#define LOG2E 1.4426950408889634f
#define SCLO -7.213475204444817f   // -5 * log2e
#define SCHI  7.213475204444817f

typedef __attribute__((ext_vector_type(8))) short bf16x8;
typedef __attribute__((ext_vector_type(4))) float f32x4;
typedef __attribute__((ext_vector_type(2))) uint u32x2;

// ---- ws layout (bytes) ----
#define WS_MFLAG 0        // 8192 u32
#define WS_DB    32768    // 8192 u16: bf16(e0-e1)
#define WS_E1B   49152    // bf16(e1)
#define WS_EMB   65536    // bf16(emiss)
#define WS_WLB   81920    // bf16(attn_w * log2e)
#define WS_WT    98304    // [32][128] u16 compress_w^T (upper 64 k-rows E-permuted)
#define WS_BL    106496   // 128 f32 bias*log2e

__device__ __forceinline__ ushort f2bf(float x) {
    union { float f; uint u; } v; v.f = x;
    uint r = v.u + 0x7fffu + ((v.u >> 16) & 1u);   // RNE
    return (ushort)(r >> 16);
}
__device__ __forceinline__ uint pk_bf16(float lo, float hi) {   // v_cvt_pk_bf16_f32
    uint r; asm("v_cvt_pk_bf16_f32 %0, %1, %2" : "=v"(r) : "v"(lo), "v"(hi)); return r;
}
__device__ __forceinline__ float bflo(uint u) { union { uint u; float f; } v; v.u = u << 16; return v.f; }
__device__ __forceinline__ float bfhi(uint u) { union { uint u; float f; } v; v.u = u & 0xffff0000u; return v.f; }

// hardware transpose read: lane reads 4 bf16 at u16-stride 16 from its own addr
#define TRR(dst, addr, IMM) \
    asm volatile("ds_read_b64_tr_b16 %0, %1 offset:" IMM : "=v"(dst) : "v"(addr))

// cross-lane exchange among lanes sharing lr (lg0..3): swaps vdst[32..63] <-> vsrc[0..31]
#define PLSWAP(a, b) asm("v_permlane32_swap_b32 %0, %1" : "+v"(a), "+v"(b))

// ---------------- kernel 1: prep ----------------
__global__ __launch_bounds__(256) void prep_kernel(
    const int* __restrict__ mask, const float* __restrict__ e0, const float* __restrict__ e1,
    const float* __restrict__ em, const float* __restrict__ aw, const float* __restrict__ ab,
    const float* __restrict__ cw,
    uint* __restrict__ mflag, ushort* __restrict__ db, ushort* __restrict__ e1b,
    ushort* __restrict__ emb, ushort* __restrict__ wlb, ushort* __restrict__ wt,
    float* __restrict__ bl)
{
    const int blk = blockIdx.x, tid = threadIdx.x;
    if (blk < 32) {                     // tables -> bf16 (+ D = e0-e1, w*log2e)
        int idx = blk * 256 + tid;      // 8192
        float e1v = e1[idx];
        e1b[idx] = f2bf(e1v);
        emb[idx] = f2bf(em[idx]);
        db[idx]  = f2bf(e0[idx] - e1v);
        wlb[idx] = f2bf(aw[idx] * LOG2E);
    } else if (blk < 64) {              // m[b,f] = any_t mask
        int idx = (blk - 32) * 256 + tid;
        int b = idx >> 7, f = idx & 127;
        const int* p = mask + b * (NT * NF) + f;
        int s = 0;
#pragma unroll
        for (int t = 0; t < NT; ++t) s += p[t * NF];
        mflag[idx] = (s != 0) ? 1u : 0u;
    } else if (blk < 80) {              // compress_w -> wt bf16 [32][128], upper half E-permuted
        int idx = (blk - 64) * 256 + tid;
        int k = idx >> 5, d = idx & 31;
        int kd;
        if (k < 64) kd = k;
        else {
            int kk = k - 64;            // E: swap bits 2 and 3 within each 32-group
            kd = 64 + ((kk & 51) | ((kk & 4) << 1) | ((kk & 8) >> 1));
        }
        wt[d * 128 + kd] = f2bf(cw[idx]);
    } else {                            // bias * log2e
        if (tid < NF) bl[tid] = ab[tid] * LOG2E;
    }
}

// ---------------- kernel 2: dual-(b,t) pipeline, register-only P/A2 exchange ----------------
// LDS: sC[2][9248] u16 = 36992 B only (strips eliminated via permlane32_swap).
// Coarse R7 schedule (compiler + 16-wave TLP handles overlap).
__global__ __launch_bounds__(512, 4) void fused_kernel(
    const float* __restrict__ input_x, const uint* __restrict__ mflag,
    const ushort* __restrict__ db, const ushort* __restrict__ e1b, const ushort* __restrict__ emb,
    const ushort* __restrict__ wlb, const float* __restrict__ blog,
    const ushort* __restrict__ wt, float* __restrict__ out)
{
    __shared__ ushort sC[2 * 9248];

    const int tid = threadIdx.x;
    const int blk = blockIdx.x;
    const int b   = blk / 24;
    const int bt0 = b * NT + (blk % 24) * 2;
    const int bt1 = bt0 + 1;

    const int wv = tid >> 6, ln = tid & 63;
    const int lr = ln & 15, lg = ln >> 4;
    const int i0 = wv << 4, irow = i0 + lr;

    // ---- hoisted per-lane globals (shared across both chains) ----
    const float bl = blog[irow];
    const float x0 = input_x[bt0 * NF + irow];
    const float x1 = input_x[bt1 * NF + irow];
    const ushort* Mrow = (mflag[b * NF + irow] ? e1b : emb) + irow * NE;
    const ushort* Drow = db + irow * NE;
    const ushort* Wrow = wlb + irow * NE;

    const int sbase = (lg >> 1) * 2312 + (lr >> 2) * 72 + (lr & 3) * 16 + (lg & 1) * 8;

    ushort* sC0 = sC;
    ushort* sC1 = sC + 9248;

    // ---- phase 1: unpack D/M/W once; c(t0), c(t1) to LDS; CW-frags in regs ----
    bf16x8 cwf0[2], cwf1[2];
#pragma unroll
    for (int ks = 0; ks < 2; ++ks) {
        const int eo = ks * 32 + lg * 8;
        uint d4[4], m4[4], w4[4];
        *(uint4*)d4 = *(const uint4*)(Drow + eo);
        *(uint4*)m4 = *(const uint4*)(Mrow + eo);
        *(uint4*)w4 = *(const uint4*)(Wrow + eo);
        uint cb0[4], cb1[4];
        union { uint u[4]; bf16x8 v; } cw0, cw1;
#pragma unroll
        for (int j = 0; j < 4; ++j) {
            float dlo = bflo(d4[j]), dhi = bfhi(d4[j]);
            float mlo = bflo(m4[j]), mhi = bfhi(m4[j]);
            float wlo = bflo(w4[j]), whi = bfhi(w4[j]);
            float c0lo = fmaf(x0, dlo, mlo), c0hi = fmaf(x0, dhi, mhi);
            float c1lo = fmaf(x1, dlo, mlo), c1hi = fmaf(x1, dhi, mhi);
            cb0[j] = pk_bf16(c0lo, c0hi);
            cb1[j] = pk_bf16(c1lo, c1hi);
            cw0.u[j] = pk_bf16(c0lo * wlo, c0hi * whi);
            cw1.u[j] = pk_bf16(c1lo * wlo, c1hi * whi);
        }
        cwf0[ks] = cw0.v; cwf1[ks] = cw1.v;
        *(uint4*)&sC0[sbase + wv * 288 + ks * 4624] = *(uint4*)cb0;
        *(uint4*)&sC1[sbase + wv * 288 + ks * 4624] = *(uint4*)cb1;
    }
    __syncthreads();                    // the ONLY barrier

    // ================= per-chain phase helpers =================
    auto run_S = [&](const ushort* base, bf16x8 w0, bf16x8 w1, f32x4* st) {
#pragma unroll
        for (int jt = 0; jt < 8; ++jt) {
            f32x4 a = (f32x4){bl, bl, bl, bl};
            bf16x8 a0 = *(bf16x8*)&base[sbase + jt * 288];
            a = __builtin_amdgcn_mfma_f32_16x16x32_bf16(a0, w0, a, 0, 0, 0);
            bf16x8 a1 = *(bf16x8*)&base[sbase + jt * 288 + 4624];
            a = __builtin_amdgcn_mfma_f32_16x16x32_bf16(a1, w1, a, 0, 0, 0);
            st[jt] = a;
        }
    };
    auto run_SM = [&](f32x4* st, uint* pp) -> float {
        float rs0 = 0.f, rs1 = 0.f, rs2 = 0.f, rs3 = 0.f;
#pragma unroll
        for (int jt = 0; jt < 8; ++jt) {
            f32x4 v = st[jt];
            float e0 = exp2f(__builtin_amdgcn_fmed3f(v[0], SCLO, SCHI));
            float e1 = exp2f(__builtin_amdgcn_fmed3f(v[1], SCLO, SCHI));
            float e2 = exp2f(__builtin_amdgcn_fmed3f(v[2], SCLO, SCHI));
            float e3 = exp2f(__builtin_amdgcn_fmed3f(v[3], SCLO, SCHI));
            if (jt == wv) {             // wave-uniform; diagonal lives in tile jt==wv
                const bool on = (lg == (lr >> 2));
                e0 = (on && (lr & 3) == 0) ? 0.f : e0;
                e1 = (on && (lr & 3) == 1) ? 0.f : e1;
                e2 = (on && (lr & 3) == 2) ? 0.f : e2;
                e3 = (on && (lr & 3) == 3) ? 0.f : e3;
            }
            rs0 += e0; rs1 += e1; rs2 += e2; rs3 += e3;
            pp[2 * jt]     = pk_bf16(e0, e1);
            pp[2 * jt + 1] = pk_bf16(e2, e3);
        }
        float rs = (rs0 + rs1) + (rs2 + rs3);
        rs += __shfl_xor(rs, 16);
        rs += __shfl_xor(rs, 32);
        return 1.0f / (rs + 1e-8f);
    };
    // AGG^T: B-frag via 2 permlane32_swap (E-permuted k-order), A via tr-reads
    auto run_AGG = [&](const ushort* base, uint* pp, f32x4* ag) {
#pragma unroll
        for (int et = 0; et < 4; ++et) ag[et] = (f32x4){0.f, 0.f, 0.f, 0.f};
        const uint tb0 = (uint)(uintptr_t)base
                       + 2u * (uint)(72 * (((lg >> 1) << 2) + (lg & 1)) + lr);
#pragma unroll
        for (int ks = 0; ks < 4; ++ks) {
            uint X0 = pp[4 * ks], X1 = pp[4 * ks + 1], X2 = pp[4 * ks + 2], X3 = pp[4 * ks + 3];
            PLSWAP(X0, X2);
            PLSWAP(X1, X3);
            union { uint u[4]; bf16x8 v; } pf;
            pf.u[0] = X0; pf.u[1] = X1; pf.u[2] = X2; pf.u[3] = X3;
            const uint tb = tb0 + 1152u * (uint)ks;
            u32x2 c0a, c0b, c1a, c1b, c2a, c2b, c3a, c3b;
            TRR(c0a, tb, "0");     TRR(c0b, tb, "144");
            TRR(c1a, tb, "4624");  TRR(c1b, tb, "4768");
            TRR(c2a, tb, "9248");  TRR(c2b, tb, "9392");
            TRR(c3a, tb, "13872"); TRR(c3b, tb, "14016");
            asm volatile("s_waitcnt lgkmcnt(0)" ::: "memory");
            __builtin_amdgcn_sched_barrier(0);
            union { u32x2 d[2]; bf16x8 v; } a0, a1, a2, a3;
            a0.d[0] = c0a; a0.d[1] = c0b;
            a1.d[0] = c1a; a1.d[1] = c1b;
            a2.d[0] = c2a; a2.d[1] = c2b;
            a3.d[0] = c3a; a3.d[1] = c3b;
            ag[0] = __builtin_amdgcn_mfma_f32_16x16x32_bf16(a0.v, pf.v, ag[0], 0, 0, 0);
            ag[1] = __builtin_amdgcn_mfma_f32_16x16x32_bf16(a1.v, pf.v, ag[1], 0, 0, 0);
            ag[2] = __builtin_amdgcn_mfma_f32_16x16x32_bf16(a2.v, pf.v, ag[2], 0, 0, 0);
            ag[3] = __builtin_amdgcn_mfma_f32_16x16x32_bf16(a3.v, pf.v, ag[3], 0, 0, 0);
        }
    };
    // epilogue: normalize, .*C, relu -> packed bf16 regs aa[8] (e-order = SM's pp order)
    auto run_EPI = [&](const ushort* base, f32x4* ag, float inv, uint* aa) {
        const int ebase = (wv * 4 + (lr >> 2)) * 72 + (lr & 3) * 16 + lg * 4;
#pragma unroll
        for (int et = 0; et < 4; ++et) {
            u32x2 cb2 = *(u32x2*)&base[ebase + et * 2312];
            float a0f = fmaxf(ag[et][0] * inv * bflo(cb2.x), 0.f);
            float a1f = fmaxf(ag[et][1] * inv * bfhi(cb2.x), 0.f);
            float a2f = fmaxf(ag[et][2] * inv * bflo(cb2.y), 0.f);
            float a3f = fmaxf(ag[et][3] * inv * bfhi(cb2.y), 0.f);
            aa[2 * et]     = pk_bf16(a0f, a1f);
            aa[2 * et + 1] = pk_bf16(a2f, a3f);
        }
    };
    // OUT: relu([C, A2]) @ Wc; A2 frags via 2 permlane32_swap per k-slice
    auto run_OUT = [&](const ushort* base, uint* aa, const bf16x8* wf, int bt) {
        f32x4 oc[2];
        oc[0] = (f32x4){0.f, 0.f, 0.f, 0.f};
        oc[1] = (f32x4){0.f, 0.f, 0.f, 0.f};
#pragma unroll
        for (int ks = 0; ks < 4; ++ks) {
            bf16x8 afr;
            if (ks < 2) {
                const uint4 cc = *(uint4*)&base[sbase + wv * 288 + ks * 4624];
                union { uint u[4]; bf16x8 v; } rl;
                asm("v_pk_max_i16 %0, %1, 0" : "=v"(rl.u[0]) : "v"(cc.x));
                asm("v_pk_max_i16 %0, %1, 0" : "=v"(rl.u[1]) : "v"(cc.y));
                asm("v_pk_max_i16 %0, %1, 0" : "=v"(rl.u[2]) : "v"(cc.z));
                asm("v_pk_max_i16 %0, %1, 0" : "=v"(rl.u[3]) : "v"(cc.w));
                afr = rl.v;
            } else {
                const int kk = ks - 2;
                uint Y0 = aa[4 * kk], Y1 = aa[4 * kk + 1], Y2 = aa[4 * kk + 2], Y3 = aa[4 * kk + 3];
                PLSWAP(Y0, Y2);
                PLSWAP(Y1, Y3);
                union { uint u[4]; bf16x8 v; } af;
                af.u[0] = Y0; af.u[1] = Y1; af.u[2] = Y2; af.u[3] = Y3;
                afr = af.v;
            }
            oc[0] = __builtin_amdgcn_mfma_f32_16x16x32_bf16(afr, wf[ks * 2 + 0], oc[0], 0, 0, 0);
            oc[1] = __builtin_amdgcn_mfma_f32_16x16x32_bf16(afr, wf[ks * 2 + 1], oc[1], 0, 0, 0);
        }
        float* op = out + bt * (NF * NCD);
#pragma unroll
        for (int dt = 0; dt < 2; ++dt)
#pragma unroll
            for (int r = 0; r < 4; ++r)
                op[(i0 + lg * 4 + r) * NCD + dt * 16 + lr] = oc[dt][r];
    };

    // ================= staggered dual-chain schedule (R7 order) =================
    f32x4 st0[8], st1[8];
    uint pp0[16], pp1[16];
    f32x4 ag0[4], ag1[4];
    uint aa0[8], aa1[8];

    run_S(sC0, cwf0[0], cwf0[1], st0);
    const float inv0 = run_SM(st0, pp0);        // st0 dead
    run_S(sC1, cwf1[0], cwf1[1], st1);
    const float inv1 = run_SM(st1, pp1);        // st1 dead

    run_AGG(sC0, pp0, ag0);                     // pp0 dead
    run_EPI(sC0, ag0, inv0, aa0);               // ag0 dead
    run_AGG(sC1, pp1, ag1);                     // pp1 dead

    bf16x8 wf[8];                               // Wt B-frags (shared by both chains)
#pragma unroll
    for (int ks = 0; ks < 4; ++ks)
#pragma unroll
        for (int dt = 0; dt < 2; ++dt)
            wf[ks * 2 + dt] = *(const bf16x8*)(wt + (dt * 16 + lr) * 128 + ks * 32 + lg * 8);

    run_EPI(sC1, ag1, inv1, aa1);               // ag1 dead
    run_OUT(sC0, aa0, wf, bt0);
    run_OUT(sC1, aa1, wf, bt1);
}

extern "C" void kernel_launch(void* const* d_in, const int* in_sizes, int n_in,
                              void* d_out, int out_size, void* d_ws, size_t ws_size,
                              hipStream_t stream) {
    const float* input_x       = (const float*)d_in[0];
    const int*   mask          = (const int*)d_in[1];
    const float* embed0        = (const float*)d_in[2];
    const float* embed1        = (const float*)d_in[3];
    const float* embed_missing = (const float*)d_in[4];
    const float* attn_w        = (const float*)d_in[5];
    const float* attn_b        = (const float*)d_in[6];
    const float* compress_w    = (const float*)d_in[7];
    float* out = (float*)d_out;

    char* ws = (char*)d_ws;
    uint*   mflag = (uint*)(ws + WS_MFLAG);
    ushort* dbp   = (ushort*)(ws + WS_DB);
    ushort* e1bp  = (ushort*)(ws + WS_E1B);
    ushort* embp  = (ushort*)(ws + WS_EMB);
    ushort* wlbp  = (ushort*)(ws + WS_WLB);
    ushort* wtp   = (ushort*)(ws + WS_WT);
    float*  blp   = (float*)(ws + WS_BL);

    hipLaunchKernelGGL(prep_kernel, dim3(81), dim3(256), 0, stream,
                       mask, embed0, embed1, embed_missing, attn_w, attn_b, compress_w,
                       mflag, dbp, e1bp, embp, wlbp, wtp, blp);
    hipLaunchKernelGGL(fused_kernel, dim3(NB * NT / 2), dim3(512), 0, stream,
                       input_x, mflag, dbp, e1bp, embp, wlbp, blp, wtp, out);
}